// Round 6
// baseline (63.785 us; speedup 1.0000x reference)
//
#include <hip/hip_runtime.h>
#include <math.h>

#define NN 512
#define DD 128
#define TEMP_INV (1.0f / 0.07f)
#define EPSF 1e-8f

// ws layout:
//   byte 0              : uint ticket            (zeroed by K1 each launch)
//   ll idx 1..4         : int64 accums {ral_s, ral_c, oal_s, oal_c} (zeroed by K1)
//   float idx 15        : vn = ||v_prog|| + eps
//   float idx 16  +512  : sv[NN]   sorted positions
//   float idx 528 +512  : rk[NN]   (int) rank of k
//   float idx 1040+512  : sqn[NN]
//   float idx 1552+512  : proj[NN]
//   float idx 4096      : fq[32][512] float4 transposed features (256 KB)
#define WS_VN   15
#define WS_SV   16
#define WS_RK   528
#define WS_SQN  1040
#define WS_PROJ 1552
#define WS_FT   4096

#define SCALE_RAL 268435456.0   // 2^28
#define SCALE_OAL 8589934592.0  // 2^33

// grid: 0..511 norms | 512 vnorm+zero | 513..516 ranks | 517..644 transpose
__global__ __launch_bounds__(128) void prep_kernel(
    const float* __restrict__ features,
    const float* __restrict__ labels,
    const float* __restrict__ v_prog,
    float* __restrict__ ws)
{
    const int b = blockIdx.x;
    const int t = threadIdx.x;
    if (b < NN) {
        __shared__ float s0[2], s1[2];
        const float* cfi = features + (b & 255) * (2 * DD) + (b >> 8) * DD;
        float x = cfi[t];
        float v = v_prog[t];
        float s = x * x, p = x * v;
        #pragma unroll
        for (int o = 32; o > 0; o >>= 1) { s += __shfl_down(s, o); p += __shfl_down(p, o); }
        if ((t & 63) == 0) { s0[t >> 6] = s; s1[t >> 6] = p; }
        __syncthreads();
        if (t == 0) {
            ws[WS_SQN  + b] = s0[0] + s0[1];
            ws[WS_PROJ + b] = s1[0] + s1[1];
        }
    } else if (b == NN) {
        __shared__ float s0[2];
        float x = v_prog[t];
        float s = x * x;
        #pragma unroll
        for (int o = 32; o > 0; o >>= 1) s += __shfl_down(s, o);
        if ((t & 63) == 0) s0[t >> 6] = s;
        __syncthreads();
        if (t == 0) {
            ws[WS_VN] = sqrtf(s0[0] + s0[1]) + EPSF;
            ((unsigned*)ws)[0] = 0u;                       // ticket
            long long* acc = (long long*)ws;
            acc[1] = 0; acc[2] = 0; acc[3] = 0; acc[4] = 0;
        }
    } else if (b <= NN + 4) {
        __shared__ __align__(16) float pos_s[NN];
        const int k = (b - (NN + 1)) * 128 + t;
        for (int m = t; m < NN; m += 128) pos_s[m] = labels[m & 255];
        __syncthreads();
        const float pk = pos_s[k];
        const float4* p4 = (const float4*)pos_s;
        int r = 0;
        #pragma unroll 8
        for (int q = 0; q < NN / 4; ++q) {
            float4 v = p4[q];
            const int m0 = 4 * q;
            r += (int)(v.x < pk) | ((int)(v.x == pk) & (int)(m0 + 0 < k));
            r += (int)(v.y < pk) | ((int)(v.y == pk) & (int)(m0 + 1 < k));
            r += (int)(v.z < pk) | ((int)(v.z == pk) & (int)(m0 + 2 < k));
            r += (int)(v.w < pk) | ((int)(v.w == pk) & (int)(m0 + 3 < k));
        }
        ws[WS_SV + r] = pk;                 // unique slot (stable tie-break)
        ((int*)ws)[WS_RK + k] = r;
    } else {
        // transpose: fq[q][n] = F[n][4q..4q+3]; block handles rows 4tb..4tb+3
        const int tb  = b - (NN + 5);
        const int q   = t & 31;
        const int row = 4 * tb + (t >> 5);
        const float4* src = (const float4*)(features + (row & 255) * (2 * DD) + (row >> 8) * DD);
        float4 v = src[q];
        *((float4*)(ws + WS_FT) + (q * NN + row)) = v;
    }
}

// One block (512 threads) per row i; thread t is both k=t and j=t.
// Coalesced phase-1 via transposed fq; int64 fixed-point atomic finale.
__global__ __launch_bounds__(512) void main_kernel(
    const float* __restrict__ features,
    const float* __restrict__ labels,
    float* __restrict__ ws,
    float* __restrict__ out)
{
    __shared__ __align__(16) float cfi_s[DD];
    __shared__ float sv_s[NN];
    __shared__ float esS[NN];
    __shared__ float wtot[8];
    __shared__ float red_s[32];
    __shared__ int is_last;

    const int i = blockIdx.x;
    const int t = threadIdx.x;

    if (t < DD) cfi_s[t] = features[(i & 255) * (2 * DD) + (i >> 8) * DD + t];
    sv_s[t] = ws[WS_SV + t];
    const int rk = ((const int*)ws)[WS_RK + t];
    __syncthreads();

    // ---- phase 1: coalesced dot(row_i, row_k) for k = t
    const float4* fq = (const float4*)(ws + WS_FT);   // fq[q*NN + n]
    const float4* c4 = (const float4*)cfi_s;
    float d0 = 0.f, d1 = 0.f, d2 = 0.f, d3 = 0.f;
    #pragma unroll 8
    for (int q = 0; q < DD / 4; ++q) {
        float4 a = fq[q * NN + t];                    // lanes -> consecutive float4
        float4 c = c4[q];                             // LDS broadcast
        d0 += a.x * c.x; d1 += a.y * c.y; d2 += a.z * c.z; d3 += a.w * c.w;
    }
    const float dot = (d0 + d1) + (d2 + d3);

    const float vn     = ws[WS_VN];
    const float pos_i  = labels[i & 255];
    const float pos_k  = labels[t & 255];
    const float sqn_i  = ws[WS_SQN + i];
    const float sqn_k  = ws[WS_SQN + t];
    const float proj_i = ws[WS_PROJ + i];
    const float proj_k = ws[WS_PROJ + t];
    const float inv_ni = 1.0f / fmaxf(sqrtf(sqn_i), 1e-12f);
    const float inv_nk = 1.0f / fmaxf(sqrtf(sqn_k), 1e-12f);
    const float sim    = dot * inv_ni * inv_nk * TEMP_INV;
    const float es     = (t == i) ? 0.0f : __expf(sim);   // k==i excluded
    esS[rk] = es;                                          // scatter to sorted slot

    float oal_sum = 0.f, oal_cnt = 0.f;
    if (pos_i < pos_k) {
        float sqd  = fmaxf(sqn_i + sqn_k - 2.0f * dot, 0.0f);
        float dist = sqrtf(fmaxf(sqd, 1e-24f));
        oal_sum = (proj_k - proj_i) / (vn * fmaxf(dist, 1e-12f));
        oal_cnt = 1.0f;
    }
    __syncthreads();

    // ---- inclusive prefix scan of esS[512]
    float s = esS[t];
    #pragma unroll
    for (int off = 1; off < 64; off <<= 1) {
        float u = __shfl_up(s, off);
        if ((t & 63) >= off) s += u;
    }
    const int wid = t >> 6;
    if ((t & 63) == 63) wtot[wid] = s;
    __syncthreads();
    float woff = 0.f;
    for (int w = 0; w < wid; ++w) woff += wtot[w];    // wave-uniform
    esS[t] = s + woff;
    __syncthreads();
    const float total = esS[NN - 1];

    // ---- denom via interval [lo,hi) of {k : |p_i - p_k| < thr}
    const float thr = fabsf(pos_i - pos_k);           // pd[i][j], j==t

    int R = 0;
    #pragma unroll
    for (int step = 256; step > 0; step >>= 1)
        if (R + step <= NN && sv_s[R + step - 1] < pos_i) R += step;
    int lo = 0;
    #pragma unroll
    for (int step = 256; step > 0; step >>= 1)
        if (lo + step <= R && !(fabsf(pos_i - sv_s[lo + step - 1]) < thr)) lo += step;
    int hi = R;
    #pragma unroll
    for (int step = 256; step > 0; step >>= 1)
        if (hi + step <= NN && (fabsf(pos_i - sv_s[hi + step - 1]) < thr)) hi += step;

    const float pe_lo = (lo > 0) ? esS[lo - 1] : 0.0f;
    const float pe_hi = (hi > 0) ? esS[hi - 1] : 0.0f;
    float ral_sum = 0.f, ral_cnt = 0.f;
    if (t != i) {
        float denom = fmaxf(pe_lo + (total - pe_hi), es);   // guard rounding; k=j in set
        const float sw = 1.0f / (1.0f + __expf(-thr));      // sigmoid(pd)
        ral_sum = (__logf(denom + EPSF) - sim) * sw;        // -log(es/(denom+eps))
        ral_cnt = 1.0f;
    }

    // ---- block reduce
    #pragma unroll
    for (int o = 32; o > 0; o >>= 1) {
        ral_sum += __shfl_down(ral_sum, o);
        ral_cnt += __shfl_down(ral_cnt, o);
        oal_sum += __shfl_down(oal_sum, o);
        oal_cnt += __shfl_down(oal_cnt, o);
    }
    if ((t & 63) == 0) {
        red_s[wid*4+0] = ral_sum; red_s[wid*4+1] = ral_cnt;
        red_s[wid*4+2] = oal_sum; red_s[wid*4+3] = oal_cnt;
    }
    __syncthreads();
    if (t == 0) {
        float rs = 0.f, rc = 0.f, os = 0.f, oc = 0.f;
        #pragma unroll
        for (int w = 0; w < 8; ++w) {
            rs += red_s[w*4+0]; rc += red_s[w*4+1];
            os += red_s[w*4+2]; oc += red_s[w*4+3];
        }
        // int64 fixed-point: order-independent => deterministic
        long long* acc = (long long*)ws;
        long long rsl = llrint((double)rs * SCALE_RAL);
        long long rcl = llrint((double)rc);
        long long osl = llrint((double)os * SCALE_OAL);
        long long ocl = llrint((double)oc);
        __hip_atomic_fetch_add(&acc[1], rsl, __ATOMIC_RELAXED, __HIP_MEMORY_SCOPE_AGENT);
        __hip_atomic_fetch_add(&acc[2], rcl, __ATOMIC_RELAXED, __HIP_MEMORY_SCOPE_AGENT);
        __hip_atomic_fetch_add(&acc[3], osl, __ATOMIC_RELAXED, __HIP_MEMORY_SCOPE_AGENT);
        __hip_atomic_fetch_add(&acc[4], ocl, __ATOMIC_RELAXED, __HIP_MEMORY_SCOPE_AGENT);
        unsigned old = __hip_atomic_fetch_add((unsigned*)ws, 1u, __ATOMIC_ACQ_REL,
                                              __HIP_MEMORY_SCOPE_AGENT);
        is_last = (old == NN - 1u);
    }
    __syncthreads();

    if (is_last && t == 0) {
        long long* acc = (long long*)ws;
        double RS = (double)__hip_atomic_load(&acc[1], __ATOMIC_RELAXED, __HIP_MEMORY_SCOPE_AGENT) / SCALE_RAL;
        double RC = (double)__hip_atomic_load(&acc[2], __ATOMIC_RELAXED, __HIP_MEMORY_SCOPE_AGENT);
        double OS = (double)__hip_atomic_load(&acc[3], __ATOMIC_RELAXED, __HIP_MEMORY_SCOPE_AGENT) / SCALE_OAL;
        double OC = (double)__hip_atomic_load(&acc[4], __ATOMIC_RELAXED, __HIP_MEMORY_SCOPE_AGENT);
        double ral = (RC > 0.0) ? RS / RC : 0.0;
        double oal = (OC > 0.0) ? -(OS / OC) : 0.0;
        out[0] = (float)(ral + oal);
    }
}

extern "C" void kernel_launch(void* const* d_in, const int* in_sizes, int n_in,
                              void* d_out, int out_size, void* d_ws, size_t ws_size,
                              hipStream_t stream) {
    const float* features = (const float*)d_in[0];
    const float* labels   = (const float*)d_in[1];
    const float* v_prog   = (const float*)d_in[2];
    float* ws  = (float*)d_ws;
    float* out = (float*)d_out;

    hipLaunchKernelGGL(prep_kernel, dim3(NN + 5 + 128), dim3(128), 0, stream,
                       features, labels, v_prog, ws);
    hipLaunchKernelGGL(main_kernel, dim3(NN), dim3(512), 0, stream,
                       features, labels, ws, out);
}

// Round 7
// 32.589 us; speedup vs baseline: 1.9572x; 1.9572x over previous
//
#include <hip/hip_runtime.h>
#include <math.h>

#define NN 512
#define DD 128
#define TEMP_INV (1.0f / 0.07f)
#define EPSF 1e-8f

// ws float-indexed layout (~1.06 MB used):
//   15            : vn = ||v_prog|| + eps
//   16   +512     : sv[NN]    sorted positions (ascending)
//   528  +512     : rk[NN]    (int) stable rank of element k
//   1040 +512     : proj[NN]  raw cf . v_prog
//   1552 +2048    : partials float[NN][4] {ral_s, ral_c, oal_s, oal_c}
//   4096 +262144  : G[NN][NN] raw Gram matrix cf @ cf^T
#define WS_VN   15
#define WS_SV   16
#define WS_RK   528
#define WS_PROJ 1040
#define WS_PART 1552
#define WS_G    4096

// prep: blocks 0..255 = gram 32x32 tiles | 256,257 = proj | 258 = vn | 259,260 = ranks
__global__ __launch_bounds__(256) void prep_kernel(
    const float* __restrict__ features,
    const float* __restrict__ labels,
    const float* __restrict__ v_prog,
    float* __restrict__ ws)
{
    const int b = blockIdx.x;
    const int t = threadIdx.x;
    if (b < 256) {
        // ---- Gram tile (tr,tc): G[32tr..+32][32tc..+32], 132-float row pad
        __shared__ __align__(16) float a_s[32 * 132];
        __shared__ __align__(16) float b_s[32 * 132];
        const int tr = b >> 4, tc = b & 15;
        #pragma unroll
        for (int it = 0; it < 4; ++it) {
            const int fidx = t + 256 * it;          // 0..1023
            const int rl = fidx >> 5, q = fidx & 31;
            const int ra = 32 * tr + rl, rb = 32 * tc + rl;
            float4 va = ((const float4*)features)[((ra & 255) * 2 + (ra >> 8)) * 32 + q];
            float4 vb = ((const float4*)features)[((rb & 255) * 2 + (rb >> 8)) * 32 + q];
            *(float4*)(a_s + rl * 132 + 4 * q) = va;    // 132 floats = 33 float4: aligned
            *(float4*)(b_s + rl * 132 + 4 * q) = vb;
        }
        __syncthreads();
        const int my = (t >> 4) * 2, mx = (t & 15) * 2;
        float c00 = 0.f, c01 = 0.f, c10 = 0.f, c11 = 0.f;
        #pragma unroll 4
        for (int q = 0; q < 32; ++q) {
            float4 a0 = *(const float4*)(a_s + (my + 0) * 132 + 4 * q);
            float4 a1 = *(const float4*)(a_s + (my + 1) * 132 + 4 * q);
            float4 b0 = *(const float4*)(b_s + (mx + 0) * 132 + 4 * q);
            float4 b1 = *(const float4*)(b_s + (mx + 1) * 132 + 4 * q);
            c00 += a0.x*b0.x + a0.y*b0.y + a0.z*b0.z + a0.w*b0.w;
            c01 += a0.x*b1.x + a0.y*b1.y + a0.z*b1.z + a0.w*b1.w;
            c10 += a1.x*b0.x + a1.y*b0.y + a1.z*b0.z + a1.w*b0.w;
            c11 += a1.x*b1.x + a1.y*b1.y + a1.z*b1.z + a1.w*b1.w;
        }
        const int gr = 32 * tr + my, gc = 32 * tc + mx;
        ws[WS_G + (gr + 0) * NN + gc + 0] = c00;
        ws[WS_G + (gr + 0) * NN + gc + 1] = c01;
        ws[WS_G + (gr + 1) * NN + gc + 0] = c10;
        ws[WS_G + (gr + 1) * NN + gc + 1] = c11;
    } else if (b < 258) {
        // ---- proj: row = (b-256)*256 + t
        __shared__ __align__(16) float vp_s[DD];
        if (t < DD) vp_s[t] = v_prog[t];
        __syncthreads();
        const int row = (b - 256) * 256 + t;
        const float4* src = (const float4*)features + ((row & 255) * 2 + (row >> 8)) * 32;
        const float4* v4 = (const float4*)vp_s;
        float p0 = 0.f, p1 = 0.f, p2 = 0.f, p3 = 0.f;
        #pragma unroll 8
        for (int q = 0; q < 32; ++q) {
            float4 a = src[q]; float4 v = v4[q];
            p0 += a.x*v.x; p1 += a.y*v.y; p2 += a.z*v.z; p3 += a.w*v.w;
        }
        ws[WS_PROJ + row] = (p0 + p1) + (p2 + p3);
    } else if (b == 258) {
        // ---- vn
        __shared__ float s0[4];
        float x = (t < DD) ? v_prog[t] : 0.f;
        float s = x * x;
        #pragma unroll
        for (int o = 32; o > 0; o >>= 1) s += __shfl_down(s, o);
        if ((t & 63) == 0) s0[t >> 6] = s;
        __syncthreads();
        if (t == 0) ws[WS_VN] = sqrtf(s0[0] + s0[1] + s0[2] + s0[3]) + EPSF;
    } else {
        // ---- ranks: k = (b-259)*256 + t
        __shared__ __align__(16) float pos_s[NN];
        const int k = (b - 259) * 256 + t;
        for (int m = t; m < NN; m += 256) pos_s[m] = labels[m & 255];
        __syncthreads();
        const float pk = pos_s[k];
        const float4* p4 = (const float4*)pos_s;
        int r = 0;
        #pragma unroll 8
        for (int q = 0; q < NN / 4; ++q) {
            float4 v = p4[q];
            const int m0 = 4 * q;
            r += (int)(v.x < pk) | ((int)(v.x == pk) & (int)(m0 + 0 < k));
            r += (int)(v.y < pk) | ((int)(v.y == pk) & (int)(m0 + 1 < k));
            r += (int)(v.z < pk) | ((int)(v.z == pk) & (int)(m0 + 2 < k));
            r += (int)(v.w < pk) | ((int)(v.w == pk) & (int)(m0 + 3 < k));
        }
        ws[WS_SV + r] = pk;                 // unique slot (stable tie-break)
        ((int*)ws)[WS_RK + k] = r;
    }
}

// One block (512 threads) per row i; thread t is both k=t and j=t.
// Phase-1 is now a single coalesced G read; searches split at rk_i, lo/hi interleaved.
__global__ __launch_bounds__(512) void main_kernel(
    const float* __restrict__ labels,
    float* __restrict__ ws)
{
    __shared__ float sv_s[NN];
    __shared__ float esS[NN];
    __shared__ float wtot[8];
    __shared__ float red_s[32];

    const int i = blockIdx.x;
    const int t = threadIdx.x;

    sv_s[t] = ws[WS_SV + t];
    const int rk_t = ((const int*)ws)[WS_RK + t];
    const int rk_i = ((const int*)ws)[WS_RK + i];      // scalar (uniform)
    const float g      = ws[WS_G + i * NN + t];        // coalesced row of Gram
    const float sqn_i  = ws[WS_G + i * NN + i];        // scalar
    const float sqn_k  = ws[WS_G + t * NN + t];        // divergent diag (L2-warm)
    const float proj_i = ws[WS_PROJ + i];
    const float proj_k = ws[WS_PROJ + t];
    const float vn     = ws[WS_VN];
    const float pos_i  = labels[i & 255];
    const float pos_k  = labels[t & 255];

    const float inv_ni = 1.0f / fmaxf(sqrtf(sqn_i), 1e-12f);
    const float inv_nk = 1.0f / fmaxf(sqrtf(sqn_k), 1e-12f);
    const float sim    = g * inv_ni * inv_nk * TEMP_INV;
    const float es     = (t == i) ? 0.0f : __expf(sim);   // k==i excluded
    esS[rk_t] = es;                                        // scatter to sorted slot

    float oal_sum = 0.f, oal_cnt = 0.f;
    if (pos_i < pos_k) {
        float sqd  = fmaxf(sqn_i + sqn_k - 2.0f * g, 0.0f);
        float dist = sqrtf(fmaxf(sqd, 1e-24f));
        oal_sum = (proj_k - proj_i) / (vn * fmaxf(dist, 1e-12f));
        oal_cnt = 1.0f;
    }
    __syncthreads();   // sv_s + esS complete

    // ---- inclusive prefix scan of esS[512]
    float s = esS[t];
    #pragma unroll
    for (int off = 1; off < 64; off <<= 1) {
        float u = __shfl_up(s, off);
        if ((t & 63) >= off) s += u;
    }
    const int wid = t >> 6;
    if ((t & 63) == 63) wtot[wid] = s;
    __syncthreads();
    float woff = 0.f;
    for (int w = 0; w < wid; ++w) woff += wtot[w];    // wave-uniform
    esS[t] = s + woff;
    __syncthreads();
    const float total = esS[NN - 1];

    // ---- denom: interval of {k : |p_i - p_k| < thr} in sorted order.
    // Split point = rk_i (ties have pd=0<thr, consistent on both sides).
    // lo and hi chains are independent -> interleaved (half the latency depth).
    const float thr = fabsf(pos_i - pos_k);           // pd[i][j], j==t
    int lo = 0, hi = rk_i;
    #pragma unroll
    for (int step = 256; step > 0; step >>= 1) {
        if (lo + step <= rk_i && !(fabsf(pos_i - sv_s[lo + step - 1]) < thr)) lo += step;
        if (hi + step <= NN   &&  (fabsf(pos_i - sv_s[hi + step - 1]) < thr)) hi += step;
    }

    const float pe_lo = (lo > 0) ? esS[lo - 1] : 0.0f;
    const float pe_hi = (hi > 0) ? esS[hi - 1] : 0.0f;
    float ral_sum = 0.f, ral_cnt = 0.f;
    if (t != i) {
        float denom = fmaxf(pe_lo + (total - pe_hi), es);   // k=j always in set
        const float sw = 1.0f / (1.0f + __expf(-thr));      // sigmoid(pd)
        ral_sum = (__logf(denom + EPSF) - sim) * sw;        // -log(es/(denom+eps))
        ral_cnt = 1.0f;
    }

    // ---- block reduce
    #pragma unroll
    for (int o = 32; o > 0; o >>= 1) {
        ral_sum += __shfl_down(ral_sum, o);
        ral_cnt += __shfl_down(ral_cnt, o);
        oal_sum += __shfl_down(oal_sum, o);
        oal_cnt += __shfl_down(oal_cnt, o);
    }
    if ((t & 63) == 0) {
        red_s[wid*4+0] = ral_sum; red_s[wid*4+1] = ral_cnt;
        red_s[wid*4+2] = oal_sum; red_s[wid*4+3] = oal_cnt;
    }
    __syncthreads();
    if (t == 0) {
        float rs = 0.f, rc = 0.f, os = 0.f, oc = 0.f;
        #pragma unroll
        for (int w = 0; w < 8; ++w) {
            rs += red_s[w*4+0]; rc += red_s[w*4+1];
            os += red_s[w*4+2]; oc += red_s[w*4+3];
        }
        float* pp = ws + WS_PART + i * 4;
        pp[0] = rs; pp[1] = rc; pp[2] = os; pp[3] = oc;
    }
}

__global__ __launch_bounds__(256) void final_kernel(
    const float* __restrict__ ws, float* __restrict__ out)
{
    __shared__ double dred[16];
    const int t = threadIdx.x;
    double rs = 0.0, rc = 0.0, os = 0.0, oc = 0.0;
    for (int b = t; b < NN; b += 256) {
        const float* p = ws + WS_PART + b * 4;
        rs += (double)p[0]; rc += (double)p[1];
        os += (double)p[2]; oc += (double)p[3];
    }
    #pragma unroll
    for (int o = 32; o > 0; o >>= 1) {
        rs += __shfl_down(rs, o);
        rc += __shfl_down(rc, o);
        os += __shfl_down(os, o);
        oc += __shfl_down(oc, o);
    }
    if ((t & 63) == 0) {
        int w = t >> 6;
        dred[w*4+0] = rs; dred[w*4+1] = rc;
        dred[w*4+2] = os; dred[w*4+3] = oc;
    }
    __syncthreads();
    if (t == 0) {
        double RS = 0, RC = 0, OS = 0, OC = 0;
        for (int w = 0; w < 4; ++w) {
            RS += dred[w*4+0]; RC += dred[w*4+1];
            OS += dred[w*4+2]; OC += dred[w*4+3];
        }
        double ral = (RC > 0.0) ? RS / RC : 0.0;
        double oal = (OC > 0.0) ? -(OS / OC) : 0.0;
        out[0] = (float)(ral + oal);
    }
}

extern "C" void kernel_launch(void* const* d_in, const int* in_sizes, int n_in,
                              void* d_out, int out_size, void* d_ws, size_t ws_size,
                              hipStream_t stream) {
    const float* features = (const float*)d_in[0];
    const float* labels   = (const float*)d_in[1];
    const float* v_prog   = (const float*)d_in[2];
    float* ws  = (float*)d_ws;
    float* out = (float*)d_out;

    hipLaunchKernelGGL(prep_kernel,  dim3(261), dim3(256), 0, stream,
                       features, labels, v_prog, ws);
    hipLaunchKernelGGL(main_kernel,  dim3(NN),  dim3(512), 0, stream, labels, ws);
    hipLaunchKernelGGL(final_kernel, dim3(1),   dim3(256), 0, stream, ws, out);
}

// Round 8
// 30.976 us; speedup vs baseline: 2.0592x; 1.0521x over previous
//
#include <hip/hip_runtime.h>
#include <math.h>

#define NN 512
#define DD 128
#define TEMP_INV (1.0f / 0.07f)
#define EPSF 1e-8f

// ws float-indexed layout (~1.06 MB used):
//   15            : vn = ||v_prog|| + eps
//   16   +512     : sv[NN]    sorted positions (ascending)
//   528  +512     : rk[NN]    (int) stable rank of element k
//   1040 +512     : proj[NN]  raw cf . v_prog
//   1552 +512     : sqn[NN]   ||cf_k||^2 (from Gram diagonal)
//   2064 +2048    : partials float[NN][4] {ral_s, ral_c, oal_s, oal_c}
//   4096 +262144  : G[NN][NN] raw Gram matrix cf @ cf^T
#define WS_VN   15
#define WS_SV   16
#define WS_RK   528
#define WS_PROJ 1040
#define WS_SQN  1552
#define WS_PART 2064
#define WS_G    4096

// prep grid: 0..1023 = gram 16x16 tiles | 1024,1025 = proj | 1026 = vn | 1027,1028 = ranks
__global__ __launch_bounds__(256) void prep_kernel(
    const float* __restrict__ features,
    const float* __restrict__ labels,
    const float* __restrict__ v_prog,
    float* __restrict__ ws)
{
    const int b = blockIdx.x;
    const int t = threadIdx.x;
    if (b < 1024) {
        // ---- Gram tile (tr,tc): G[16tr..+16][16tc..+16]; 132-float padded rows
        __shared__ __align__(16) float a_s[16 * 132];
        __shared__ __align__(16) float b_s[16 * 132];
        const int tr = b >> 5, tc = b & 31;
        {
            const int rl = t >> 5, q = t & 31;          // 8 rows per half
            const int ra0 = 16 * tr + rl, rb0 = 16 * tc + rl;
            const int ra1 = ra0 + 8,      rb1 = rb0 + 8;
            float4 va0 = ((const float4*)features)[((ra0 & 255) * 2 + (ra0 >> 8)) * 32 + q];
            float4 vb0 = ((const float4*)features)[((rb0 & 255) * 2 + (rb0 >> 8)) * 32 + q];
            float4 va1 = ((const float4*)features)[((ra1 & 255) * 2 + (ra1 >> 8)) * 32 + q];
            float4 vb1 = ((const float4*)features)[((rb1 & 255) * 2 + (rb1 >> 8)) * 32 + q];
            *(float4*)(a_s + (rl + 0) * 132 + 4 * q) = va0;
            *(float4*)(b_s + (rl + 0) * 132 + 4 * q) = vb0;
            *(float4*)(a_s + (rl + 8) * 132 + 4 * q) = va1;
            *(float4*)(b_s + (rl + 8) * 132 + 4 * q) = vb1;
        }
        __syncthreads();
        const int y = t >> 4, x = t & 15;
        const float4* arow = (const float4*)(a_s + y * 132);
        const float4* brow = (const float4*)(b_s + x * 132);
        float c0 = 0.f, c1 = 0.f, c2 = 0.f, c3 = 0.f;
        #pragma unroll 8
        for (int q = 0; q < 32; ++q) {
            float4 a = arow[q]; float4 v = brow[q];
            c0 += a.x * v.x; c1 += a.y * v.y; c2 += a.z * v.z; c3 += a.w * v.w;
        }
        const float c = (c0 + c1) + (c2 + c3);
        const int gr = 16 * tr + y, gc = 16 * tc + x;
        ws[WS_G + gr * NN + gc] = c;
        if (gr == gc) ws[WS_SQN + gr] = c;              // diagonal -> sqn[]
    } else if (b < 1026) {
        // ---- proj: row = (b-1024)*256 + t
        __shared__ __align__(16) float vp_s[DD];
        if (t < DD) vp_s[t] = v_prog[t];
        __syncthreads();
        const int row = (b - 1024) * 256 + t;
        const float4* src = (const float4*)features + ((row & 255) * 2 + (row >> 8)) * 32;
        const float4* v4 = (const float4*)vp_s;
        float p0 = 0.f, p1 = 0.f, p2 = 0.f, p3 = 0.f;
        #pragma unroll 8
        for (int q = 0; q < 32; ++q) {
            float4 a = src[q]; float4 v = v4[q];
            p0 += a.x*v.x; p1 += a.y*v.y; p2 += a.z*v.z; p3 += a.w*v.w;
        }
        ws[WS_PROJ + row] = (p0 + p1) + (p2 + p3);
    } else if (b == 1026) {
        // ---- vn
        __shared__ float s0[4];
        float x = (t < DD) ? v_prog[t] : 0.f;
        float s = x * x;
        #pragma unroll
        for (int o = 32; o > 0; o >>= 1) s += __shfl_down(s, o);
        if ((t & 63) == 0) s0[t >> 6] = s;
        __syncthreads();
        if (t == 0) ws[WS_VN] = sqrtf(s0[0] + s0[1] + s0[2] + s0[3]) + EPSF;
    } else {
        // ---- ranks: k = (b-1027)*256 + t
        __shared__ __align__(16) float pos_s[NN];
        const int k = (b - 1027) * 256 + t;
        for (int m = t; m < NN; m += 256) pos_s[m] = labels[m & 255];
        __syncthreads();
        const float pk = pos_s[k];
        const float4* p4 = (const float4*)pos_s;
        int r = 0;
        #pragma unroll 8
        for (int q = 0; q < NN / 4; ++q) {
            float4 v = p4[q];
            const int m0 = 4 * q;
            r += (int)(v.x < pk) | ((int)(v.x == pk) & (int)(m0 + 0 < k));
            r += (int)(v.y < pk) | ((int)(v.y == pk) & (int)(m0 + 1 < k));
            r += (int)(v.z < pk) | ((int)(v.z == pk) & (int)(m0 + 2 < k));
            r += (int)(v.w < pk) | ((int)(v.w == pk) & (int)(m0 + 3 < k));
        }
        ws[WS_SV + r] = pk;                 // unique slot (stable tie-break)
        ((int*)ws)[WS_RK + k] = r;
    }
}

// One block (512 threads) per row i; thread t is both k=t and j=t.
__global__ __launch_bounds__(512) void main_kernel(
    const float* __restrict__ labels,
    float* __restrict__ ws)
{
    __shared__ float sv_s[NN];
    __shared__ float esS[NN];
    __shared__ float wtot[8];
    __shared__ float red_s[32];

    const int i = blockIdx.x;
    const int t = threadIdx.x;

    sv_s[t] = ws[WS_SV + t];
    const int rk_t = ((const int*)ws)[WS_RK + t];
    const int rk_i = ((const int*)ws)[WS_RK + i];      // uniform
    const float g      = ws[WS_G + i * NN + t];        // coalesced Gram row
    const float sqn_i  = ws[WS_SQN + i];               // uniform
    const float sqn_k  = ws[WS_SQN + t];               // coalesced
    const float proj_i = ws[WS_PROJ + i];
    const float proj_k = ws[WS_PROJ + t];
    const float vn     = ws[WS_VN];
    const float pos_i  = labels[i & 255];
    const float pos_k  = labels[t & 255];

    const float inv_ni = 1.0f / fmaxf(sqrtf(sqn_i), 1e-12f);
    const float inv_nk = 1.0f / fmaxf(sqrtf(sqn_k), 1e-12f);
    const float sim    = g * inv_ni * inv_nk * TEMP_INV;
    const float es     = (t == i) ? 0.0f : __expf(sim);   // k==i excluded
    esS[rk_t] = es;                                        // scatter to sorted slot

    float oal_sum = 0.f, oal_cnt = 0.f;
    if (pos_i < pos_k) {
        float sqd  = fmaxf(sqn_i + sqn_k - 2.0f * g, 0.0f);
        float dist = sqrtf(fmaxf(sqd, 1e-24f));
        oal_sum = (proj_k - proj_i) / (vn * fmaxf(dist, 1e-12f));
        oal_cnt = 1.0f;
    }
    __syncthreads();   // sv_s + esS complete

    // ---- inclusive prefix scan of esS[512]
    float s = esS[t];
    #pragma unroll
    for (int off = 1; off < 64; off <<= 1) {
        float u = __shfl_up(s, off);
        if ((t & 63) >= off) s += u;
    }
    const int wid = t >> 6;
    if ((t & 63) == 63) wtot[wid] = s;
    __syncthreads();
    float woff = 0.f;
    for (int w = 0; w < wid; ++w) woff += wtot[w];    // wave-uniform
    esS[t] = s + woff;
    __syncthreads();
    const float total = esS[NN - 1];

    // ---- denom: interval of {k : |p_i - p_k| < thr}; split at rk_i; lo/hi interleaved
    const float thr = fabsf(pos_i - pos_k);           // pd[i][j], j==t
    int lo = 0, hi = rk_i;
    #pragma unroll
    for (int step = 256; step > 0; step >>= 1) {
        if (lo + step <= rk_i && !(fabsf(pos_i - sv_s[lo + step - 1]) < thr)) lo += step;
        if (hi + step <= NN   &&  (fabsf(pos_i - sv_s[hi + step - 1]) < thr)) hi += step;
    }

    const float pe_lo = (lo > 0) ? esS[lo - 1] : 0.0f;
    const float pe_hi = (hi > 0) ? esS[hi - 1] : 0.0f;
    float ral_sum = 0.f, ral_cnt = 0.f;
    if (t != i) {
        float denom = fmaxf(pe_lo + (total - pe_hi), es);   // k=j always in set
        const float sw = 1.0f / (1.0f + __expf(-thr));      // sigmoid(pd)
        ral_sum = (__logf(denom + EPSF) - sim) * sw;        // -log(es/(denom+eps))
        ral_cnt = 1.0f;
    }

    // ---- block reduce
    #pragma unroll
    for (int o = 32; o > 0; o >>= 1) {
        ral_sum += __shfl_down(ral_sum, o);
        ral_cnt += __shfl_down(ral_cnt, o);
        oal_sum += __shfl_down(oal_sum, o);
        oal_cnt += __shfl_down(oal_cnt, o);
    }
    if ((t & 63) == 0) {
        red_s[wid*4+0] = ral_sum; red_s[wid*4+1] = ral_cnt;
        red_s[wid*4+2] = oal_sum; red_s[wid*4+3] = oal_cnt;
    }
    __syncthreads();
    if (t == 0) {
        float rs = 0.f, rc = 0.f, os = 0.f, oc = 0.f;
        #pragma unroll
        for (int w = 0; w < 8; ++w) {
            rs += red_s[w*4+0]; rc += red_s[w*4+1];
            os += red_s[w*4+2]; oc += red_s[w*4+3];
        }
        float* pp = ws + WS_PART + i * 4;
        pp[0] = rs; pp[1] = rc; pp[2] = os; pp[3] = oc;
    }
}

__global__ __launch_bounds__(256) void final_kernel(
    const float* __restrict__ ws, float* __restrict__ out)
{
    __shared__ double dred[16];
    const int t = threadIdx.x;
    double rs = 0.0, rc = 0.0, os = 0.0, oc = 0.0;
    for (int b = t; b < NN; b += 256) {
        const float* p = ws + WS_PART + b * 4;
        rs += (double)p[0]; rc += (double)p[1];
        os += (double)p[2]; oc += (double)p[3];
    }
    #pragma unroll
    for (int o = 32; o > 0; o >>= 1) {
        rs += __shfl_down(rs, o);
        rc += __shfl_down(rc, o);
        os += __shfl_down(os, o);
        oc += __shfl_down(oc, o);
    }
    if ((t & 63) == 0) {
        int w = t >> 6;
        dred[w*4+0] = rs; dred[w*4+1] = rc;
        dred[w*4+2] = os; dred[w*4+3] = oc;
    }
    __syncthreads();
    if (t == 0) {
        double RS = 0, RC = 0, OS = 0, OC = 0;
        for (int w = 0; w < 4; ++w) {
            RS += dred[w*4+0]; RC += dred[w*4+1];
            OS += dred[w*4+2]; OC += dred[w*4+3];
        }
        double ral = (RC > 0.0) ? RS / RC : 0.0;
        double oal = (OC > 0.0) ? -(OS / OC) : 0.0;
        out[0] = (float)(ral + oal);
    }
}

extern "C" void kernel_launch(void* const* d_in, const int* in_sizes, int n_in,
                              void* d_out, int out_size, void* d_ws, size_t ws_size,
                              hipStream_t stream) {
    const float* features = (const float*)d_in[0];
    const float* labels   = (const float*)d_in[1];
    const float* v_prog   = (const float*)d_in[2];
    float* ws  = (float*)d_ws;
    float* out = (float*)d_out;

    hipLaunchKernelGGL(prep_kernel,  dim3(1029), dim3(256), 0, stream,
                       features, labels, v_prog, ws);
    hipLaunchKernelGGL(main_kernel,  dim3(NN),   dim3(512), 0, stream, labels, ws);
    hipLaunchKernelGGL(final_kernel, dim3(1),    dim3(256), 0, stream, ws, out);
}